// Round 1
// baseline (147.331 us; speedup 1.0000x reference)
//
#include <hip/hip_runtime.h>

#define BATCH 8
#define HH 544
#define WW 960
#define HWSZ (HH * WW)
#define XQ (WW / 4)   // 240 quads per row

// One thread computes 4 consecutive output pixels (one float4).
// out[b,y,x] = sum_{kh,kw} f_pad[b, y+kh-1, x+kw-1] * w[b, kh*3+kw, y, x]
// with w = |aff| / sum_c |aff| computed on the fly (same every iteration).
__global__ __launch_bounds__(256) void affprop_iter(
    const float* __restrict__ aff,
    const float* __restrict__ fin,
    float* __restrict__ fout)
{
    int t = blockIdx.x * 256 + threadIdx.x;
    int xq   = t % XQ;
    int rest = t / XQ;
    int y = rest % HH;
    int b = rest / HH;
    int x = xq * 4;

    // ---- load 9 affinity planes (float4 each), abs + per-pixel sum ----
    const float* ab = aff + (size_t)b * 9 * HWSZ + (size_t)y * WW + x;
    float4 av[9];
#pragma unroll
    for (int c = 0; c < 9; ++c)
        av[c] = *reinterpret_cast<const float4*>(ab + (size_t)c * HWSZ);

    float4 s = make_float4(0.f, 0.f, 0.f, 0.f);
#pragma unroll
    for (int c = 0; c < 9; ++c) {
        av[c].x = fabsf(av[c].x); s.x += av[c].x;
        av[c].y = fabsf(av[c].y); s.y += av[c].y;
        av[c].z = fabsf(av[c].z); s.z += av[c].z;
        av[c].w = fabsf(av[c].w); s.w += av[c].w;
    }
    float4 rinv;
    rinv.x = 1.0f / s.x;
    rinv.y = 1.0f / s.y;
    rinv.z = 1.0f / s.z;
    rinv.w = 1.0f / s.w;

    // ---- gather 3x3 neighborhood rows and accumulate ----
    float acc0 = 0.f, acc1 = 0.f, acc2 = 0.f, acc3 = 0.f;
    const float* fb = fin + (size_t)b * HWSZ;

#pragma unroll
    for (int r = 0; r < 3; ++r) {
        int yy = y + r - 1;
        float fr0, fr1, fr2, fr3, fr4, fr5;  // x-1 .. x+4
        if (yy >= 0 && yy < HH) {
            const float* row = fb + (size_t)yy * WW + x;
            float4 m = *reinterpret_cast<const float4*>(row);
            fr0 = (x > 0)       ? row[-1] : 0.0f;
            fr1 = m.x; fr2 = m.y; fr3 = m.z; fr4 = m.w;
            fr5 = (x + 4 < WW)  ? row[4]  : 0.0f;
        } else {
            fr0 = fr1 = fr2 = fr3 = fr4 = fr5 = 0.0f;
        }
#pragma unroll
        for (int kw = 0; kw < 3; ++kw) {
            const float4 a = av[r * 3 + kw];
            // weight per pixel j = a[j] * rinv[j]; input pixel = fr[j + kw]
            float f0 = (kw == 0) ? fr0 : (kw == 1) ? fr1 : fr2;
            float f1 = (kw == 0) ? fr1 : (kw == 1) ? fr2 : fr3;
            float f2 = (kw == 0) ? fr2 : (kw == 1) ? fr3 : fr4;
            float f3 = (kw == 0) ? fr3 : (kw == 1) ? fr4 : fr5;
            acc0 = fmaf(a.x * rinv.x, f0, acc0);
            acc1 = fmaf(a.y * rinv.y, f1, acc1);
            acc2 = fmaf(a.z * rinv.z, f2, acc2);
            acc3 = fmaf(a.w * rinv.w, f3, acc3);
        }
    }

    float4 o = make_float4(acc0, acc1, acc2, acc3);
    *reinterpret_cast<float4*>(fout + (size_t)b * HWSZ + (size_t)y * WW + x) = o;
}

extern "C" void kernel_launch(void* const* d_in, const int* in_sizes, int n_in,
                              void* d_out, int out_size, void* d_ws, size_t ws_size,
                              hipStream_t stream) {
    const float* aff  = (const float*)d_in[0];
    const float* feat = (const float*)d_in[1];
    float* out = (float*)d_out;
    float* ws  = (float*)d_ws;

    const int total  = BATCH * HH * XQ;       // 1,044,480 threads
    const int blocks = total / 256;           // 4080 (exact)

    // 4 iterations, ping-pong: feat -> ws -> out -> ws -> out
    affprop_iter<<<blocks, 256, 0, stream>>>(aff, feat, ws);
    affprop_iter<<<blocks, 256, 0, stream>>>(aff, ws,   out);
    affprop_iter<<<blocks, 256, 0, stream>>>(aff, out,  ws);
    affprop_iter<<<blocks, 256, 0, stream>>>(aff, ws,   out);
}

// Round 2
// 70.350 us; speedup vs baseline: 2.0943x; 2.0943x over previous
//
#include <hip/hip_runtime.h>

#define BATCH 8
#define HH 544
#define WW 960
#define HWSZ (HH * WW)
#define TILE 56          // output tile per block
#define REGN 64          // region = TILE + 2*4 halo
#define ST 68            // LDS row stride in floats (66 cols used + pad)
#define NTY 10           // ceil(544/56)
#define NTX 18           // ceil(960/56)

// F(y,x) for region coords y,x in [-1, REGN] lives at lds[(y+1)*ST + (x+1)].
// Ring cells (y or x == -1 or REGN) stay zero forever (zero-pad emulation).

__global__ __launch_bounds__(1024) void affprop_fused(
    const float* __restrict__ aff,
    const float* __restrict__ feat,
    float* __restrict__ out)
{
    __shared__ float lds[66 * ST];

    const int tid = threadIdx.x;
    const int q   = tid & 15;      // x-quad within region (0..15), pixels 4q..4q+3
    const int ry  = tid >> 4;      // region row (0..63)
    const int b   = blockIdx.z;
    const int oy  = blockIdx.y * TILE - 4;   // region origin in image coords
    const int ox  = blockIdx.x * TILE - 4;   // multiple of 4 (56tx-4)

    // ---- zero entire LDS (ring must be 0; interior overwritten below) ----
    for (int i = tid; i < 66 * ST; i += 1024) lds[i] = 0.0f;

    const int yimg = oy + ry;
    const int xq   = ox + 4 * q;   // quad start, multiple of 4 -> all-or-nothing in x
    const bool inp = (yimg >= 0) && (yimg < HH) && (xq >= 0) && (xq < WW);

    // ---- load feature quad (before barrier; store after) ----
    float4 f0 = make_float4(0.f, 0.f, 0.f, 0.f);
    if (inp)
        f0 = *reinterpret_cast<const float4*>(
            feat + (size_t)b * HWSZ + (size_t)yimg * WW + xq);

    // ---- load 9 affinity planes, abs, normalize -> weights in registers ----
    float4 w[9];
#pragma unroll
    for (int c = 0; c < 9; ++c) w[c] = make_float4(0.f, 0.f, 0.f, 0.f);
    if (inp) {
        const float* ap = aff + (size_t)b * 9 * HWSZ + (size_t)yimg * WW + xq;
        float4 s = make_float4(0.f, 0.f, 0.f, 0.f);
#pragma unroll
        for (int c = 0; c < 9; ++c) {
            float4 v = *reinterpret_cast<const float4*>(ap + (size_t)c * HWSZ);
            v.x = fabsf(v.x); v.y = fabsf(v.y); v.z = fabsf(v.z); v.w = fabsf(v.w);
            s.x += v.x; s.y += v.y; s.z += v.z; s.w += v.w;
            w[c] = v;
        }
        float4 r;
        r.x = 1.0f / s.x; r.y = 1.0f / s.y; r.z = 1.0f / s.z; r.w = 1.0f / s.w;
#pragma unroll
        for (int c = 0; c < 9; ++c) {
            w[c].x *= r.x; w[c].y *= r.y; w[c].z *= r.z; w[c].w *= r.w;
        }
    }

    __syncthreads();               // LDS zeroing done
    if (inp) {                     // scalar stores (col +1 shift breaks f4 alignment)
        float* d = &lds[(ry + 1) * ST + 4 * q + 1];
        d[0] = f0.x; d[1] = f0.y; d[2] = f0.z; d[3] = f0.w;
    }
    __syncthreads();               // initial feature visible

    // ---- 4 fused iterations; after iter k, pixels at region-distance >= k exact ----
    float4 acc;
#pragma unroll
    for (int it = 0; it < 4; ++it) {
        acc = make_float4(0.f, 0.f, 0.f, 0.f);
#pragma unroll
        for (int dy = 0; dy < 3; ++dy) {
            const int yy = ry + dy - 1;                 // -1..64, always in array
            const float* base = &lds[(yy + 1) * ST + 4 * q];   // = F(yy, 4q-1), 16B aligned
            float4 A = *reinterpret_cast<const float4*>(base);     // x-1,x0,x1,x2
            float2 B = *reinterpret_cast<const float2*>(base + 4); // x3,x4
            const float4 wl = w[3 * dy + 0];
            const float4 wc = w[3 * dy + 1];
            const float4 wr = w[3 * dy + 2];
            acc.x = fmaf(wl.x, A.x, fmaf(wc.x, A.y, fmaf(wr.x, A.z, acc.x)));
            acc.y = fmaf(wl.y, A.y, fmaf(wc.y, A.z, fmaf(wr.y, A.w, acc.y)));
            acc.z = fmaf(wl.z, A.z, fmaf(wc.z, A.w, fmaf(wr.z, B.x, acc.z)));
            acc.w = fmaf(wl.w, A.w, fmaf(wc.w, B.x, fmaf(wr.w, B.y, acc.w)));
        }
        if (it < 3) {              // last iteration's values consumed from regs
            __syncthreads();       // all reads of old state done
            if (inp) {
                float* d = &lds[(ry + 1) * ST + 4 * q + 1];
                d[0] = acc.x; d[1] = acc.y; d[2] = acc.z; d[3] = acc.w;
            }
            __syncthreads();       // new state visible
        }
    }

    // ---- write final tile: region coords [4,60)x[4,60), thread's own acc ----
    if (ry >= 4 && ry < 4 + TILE && q >= 1 && q < 15) {
        const int yo = oy + ry;            // >= 0 always here
        const int xo = ox + 4 * q;         // >= 0 always here
        if (yo < HH && xo < WW) {          // x all-or-nothing (xo mult of 4)
            *reinterpret_cast<float4*>(
                out + (size_t)b * HWSZ + (size_t)yo * WW + xo) = acc;
        }
    }
}

extern "C" void kernel_launch(void* const* d_in, const int* in_sizes, int n_in,
                              void* d_out, int out_size, void* d_ws, size_t ws_size,
                              hipStream_t stream) {
    const float* aff  = (const float*)d_in[0];
    const float* feat = (const float*)d_in[1];
    float* out = (float*)d_out;
    (void)d_ws; (void)ws_size;

    dim3 grid(NTX, NTY, BATCH);   // 18 x 10 x 8 = 1440 blocks
    affprop_fused<<<grid, 1024, 0, stream>>>(aff, feat, out);
}

// Round 3
// 61.216 us; speedup vs baseline: 2.4068x; 1.1492x over previous
//
#include <hip/hip_runtime.h>

#define BATCH 8
#define HH 544
#define WW 960
#define HWSZ (HH * WW)
#define OTY 24            // output tile rows
#define OTX 56            // output tile cols (14 quads)
#define LROWS 34          // region rows 0..31 at LDS rows 1..32, rings 0 & 33
#define LCELLS 18         // 16 interior quads (cells 1..16) + ring cells 0,17
#define LBUF (LROWS * LCELLS)   // 612 float4 cells per buffer
#define NTX 18            // ceil(960/56)
#define NTY 23            // ceil(544/24)

// Region = 64x32 pixels at image origin (ox,oy) = (56*bx-4, 24*by-4).
// Thread (q,ry), q=tid&15, ry=tid>>4 owns quad x=[4q..4q+3], row ry.
// LDS cell (buf,row,cell): feature F(region y, x-quad) at row=y+1, cell=q+1.
// Ring cells stay 0 forever; validity shrinks 1 ring/iteration; after 4
// iterations region rows [4,28) x quads [1,15) are exact -> 56x24 output.

__global__ __launch_bounds__(512) void affprop_fused(
    const float* __restrict__ aff,
    const float* __restrict__ feat,
    float* __restrict__ out)
{
    __shared__ float4 lds4[2 * LBUF];

    const int tid = threadIdx.x;
    const int q   = tid & 15;
    const int ry  = tid >> 4;               // 0..31
    const int b   = blockIdx.z;
    const int oy  = blockIdx.y * OTY - 4;
    const int ox  = blockIdx.x * OTX - 4;   // multiple of 4

    const int yimg = oy + ry;
    const int xq   = ox + 4 * q;
    const bool inp = (yimg >= 0) && (yimg < HH) && (xq >= 0) && (xq < WW);

    // ---- issue all global loads up front (ILP) ----
    float4 f0 = make_float4(0.f, 0.f, 0.f, 0.f);
    float4 w[9];
#pragma unroll
    for (int c = 0; c < 9; ++c) w[c] = make_float4(0.f, 0.f, 0.f, 0.f);
    if (inp) {
        const float* ap = aff + (size_t)b * 9 * HWSZ + (size_t)yimg * WW + xq;
        f0 = *reinterpret_cast<const float4*>(
            feat + (size_t)b * HWSZ + (size_t)yimg * WW + xq);
#pragma unroll
        for (int c = 0; c < 9; ++c)
            w[c] = *reinterpret_cast<const float4*>(ap + (size_t)c * HWSZ);
        float4 s = make_float4(0.f, 0.f, 0.f, 0.f);
#pragma unroll
        for (int c = 0; c < 9; ++c) {
            w[c].x = fabsf(w[c].x); s.x += w[c].x;
            w[c].y = fabsf(w[c].y); s.y += w[c].y;
            w[c].z = fabsf(w[c].z); s.z += w[c].z;
            w[c].w = fabsf(w[c].w); s.w += w[c].w;
        }
        float4 r;
        r.x = 1.0f / s.x; r.y = 1.0f / s.y; r.z = 1.0f / s.z; r.w = 1.0f / s.w;
#pragma unroll
        for (int c = 0; c < 9; ++c) {
            w[c].x *= r.x; w[c].y *= r.y; w[c].z *= r.z; w[c].w *= r.w;
        }
    }

    // ---- zero ring cells only (disjoint from interior stores -> no barrier
    //      needed between this and the f0 stores) ----
    // per buffer: rows 0 & 33 full (36 cells) + rows 1..32 cells {0,17} (64) = 100
    if (tid < 200) {
        const int buf = (tid >= 100) ? 1 : 0;
        const int j = tid - 100 * buf;
        int row, cell;
        if (j < 36) { row = (j < 18) ? 0 : 33; cell = (j < 18) ? j : j - 18; }
        else { const int k = j - 36; row = 1 + (k >> 1); cell = (k & 1) ? 17 : 0; }
        lds4[buf * LBUF + row * LCELLS + cell] = make_float4(0.f, 0.f, 0.f, 0.f);
    }

    // ---- store initial feature (out-of-image threads store 0) ----
    lds4[(ry + 1) * LCELLS + (q + 1)] = f0;
    __syncthreads();

    // ---- 4 fused iterations, double-buffered, 1 barrier each ----
    float4 acc;
    int cur = 0;
#pragma unroll
    for (int it = 0; it < 4; ++it) {
        acc = make_float4(0.f, 0.f, 0.f, 0.f);
#pragma unroll
        for (int r = 0; r < 3; ++r) {
            const float4 m = lds4[cur * LBUF + (ry + r) * LCELLS + (q + 1)];
            float left  = __shfl_up(m.w, 1);   if (q == 0)  left  = 0.f;
            float right = __shfl_down(m.x, 1); if (q == 15) right = 0.f;
            const float4 wl = w[3 * r + 0];
            const float4 wc = w[3 * r + 1];
            const float4 wr = w[3 * r + 2];
            acc.x = fmaf(wl.x, left, fmaf(wc.x, m.x, fmaf(wr.x, m.y, acc.x)));
            acc.y = fmaf(wl.y, m.x,  fmaf(wc.y, m.y, fmaf(wr.y, m.z, acc.y)));
            acc.z = fmaf(wl.z, m.y,  fmaf(wc.z, m.z, fmaf(wr.z, m.w, acc.z)));
            acc.w = fmaf(wl.w, m.z,  fmaf(wc.w, m.w, fmaf(wr.w, right, acc.w)));
        }
        if (it < 3) {
            lds4[(cur ^ 1) * LBUF + (ry + 1) * LCELLS + (q + 1)] = acc;
            __syncthreads();
            cur ^= 1;
        }
    }

    // ---- write final 56x24 tile from registers ----
    if (ry >= 4 && ry < 4 + OTY && q >= 1 && q < 15) {
        const int yo = oy + ry;
        const int xo = ox + 4 * q;
        if (yo < HH && xo < WW)
            *reinterpret_cast<float4*>(
                out + (size_t)b * HWSZ + (size_t)yo * WW + xo) = acc;
    }
}

extern "C" void kernel_launch(void* const* d_in, const int* in_sizes, int n_in,
                              void* d_out, int out_size, void* d_ws, size_t ws_size,
                              hipStream_t stream) {
    const float* aff  = (const float*)d_in[0];
    const float* feat = (const float*)d_in[1];
    float* out = (float*)d_out;
    (void)d_ws; (void)ws_size;

    dim3 grid(NTX, NTY, BATCH);   // 18 x 23 x 8 = 3312 blocks
    affprop_fused<<<grid, 512, 0, stream>>>(aff, feat, out);
}

// Round 4
// 56.732 us; speedup vs baseline: 2.5970x; 1.0790x over previous
//
#include <hip/hip_runtime.h>

#define BATCH 8
#define HH 544
#define WW 960
#define HWSZ (HH * WW)
#define OTY 56            // output tile rows
#define OTX 56            // output tile cols (14 quads)
#define LROWS 66          // region rows -1..64 at LDS rows 0..65 (rows 0,65 = zero ring)
#define LCELLS 16         // 16 interior quads; x-halo handled by shfl, no x-ring cells
#define LBUF (LROWS * LCELLS)   // 1056 float4 cells per buffer (16.9 KB)
#define NTX 18            // ceil(960/56)
#define NTY 10            // ceil(544/56)

// Region = 64x64 pixels at image origin (ox,oy) = (56*bx-4, 56*by-4).
// Thread (q,ry), q=tid&15, ry=tid>>4 owns quad x=[4q..4q+3], row ry (0..63).
// LDS cell (buf,row,cell): feature F(region row ry, quad q) at row=ry+1, cell=q.
// Row rings (LDS rows 0,65) stay 0; x edges via shfl + select-0.
// Validity shrinks 1 ring/iteration; after 4 iterations region rows [4,60) x
// quads [1,15) are exact -> 56x56 output.
// Weights of region rows 0 and 63 (distance-0 pixels) are never consumed by
// any surviving value -> skip those 9-plane loads entirely.

__global__ __launch_bounds__(1024) void affprop_fused(
    const float* __restrict__ aff,
    const float* __restrict__ feat,
    float* __restrict__ out)
{
    __shared__ float4 lds4[2 * LBUF];

    const int tid = threadIdx.x;
    const int q   = tid & 15;
    const int ry  = tid >> 4;               // 0..63
    const int b   = blockIdx.z;
    const int oy  = blockIdx.y * OTY - 4;
    const int ox  = blockIdx.x * OTX - 4;   // multiple of 4

    const int yimg = oy + ry;
    const int xq   = ox + 4 * q;
    const bool inp  = (yimg >= 0) && (yimg < HH) && (xq >= 0) && (xq < WW);
    const bool wrow = inp && (ry >= 1) && (ry <= 62);   // weights actually needed

    // ---- issue global loads up front ----
    float4 f0 = make_float4(0.f, 0.f, 0.f, 0.f);
    float4 w[9];
#pragma unroll
    for (int c = 0; c < 9; ++c) w[c] = make_float4(0.f, 0.f, 0.f, 0.f);
    if (inp)
        f0 = *reinterpret_cast<const float4*>(
            feat + (size_t)b * HWSZ + (size_t)yimg * WW + xq);
    if (wrow) {
        const float* ap = aff + (size_t)b * 9 * HWSZ + (size_t)yimg * WW + xq;
#pragma unroll
        for (int c = 0; c < 9; ++c)
            w[c] = *reinterpret_cast<const float4*>(ap + (size_t)c * HWSZ);
        float4 s = make_float4(0.f, 0.f, 0.f, 0.f);
#pragma unroll
        for (int c = 0; c < 9; ++c) {
            w[c].x = fabsf(w[c].x); s.x += w[c].x;
            w[c].y = fabsf(w[c].y); s.y += w[c].y;
            w[c].z = fabsf(w[c].z); s.z += w[c].z;
            w[c].w = fabsf(w[c].w); s.w += w[c].w;
        }
        float4 r;
        r.x = 1.0f / s.x; r.y = 1.0f / s.y; r.z = 1.0f / s.z; r.w = 1.0f / s.w;
#pragma unroll
        for (int c = 0; c < 9; ++c) {
            w[c].x *= r.x; w[c].y *= r.y; w[c].z *= r.z; w[c].w *= r.w;
        }
    }

    // ---- zero the 4 ring rows (rows 0,65 of both buffers); disjoint from
    //      interior stores (rows 1..64) so no extra barrier needed ----
    if (tid < 64) {
        const int buf  = tid >> 5;
        const int row  = ((tid >> 4) & 1) ? (LROWS - 1) : 0;
        lds4[buf * LBUF + row * LCELLS + (tid & 15)] =
            make_float4(0.f, 0.f, 0.f, 0.f);
    }

    // ---- store initial feature (out-of-image threads store 0) ----
    lds4[(ry + 1) * LCELLS + q] = f0;
    __syncthreads();

    // ---- 4 fused iterations, double-buffered, 1 barrier each ----
    float4 acc;
    int cur = 0;
#pragma unroll
    for (int it = 0; it < 4; ++it) {
        acc = make_float4(0.f, 0.f, 0.f, 0.f);
#pragma unroll
        for (int r = 0; r < 3; ++r) {
            const float4 m = lds4[cur * LBUF + (ry + r) * LCELLS + q];
            float left  = __shfl_up(m.w, 1);   if (q == 0)  left  = 0.f;
            float right = __shfl_down(m.x, 1); if (q == 15) right = 0.f;
            const float4 wl = w[3 * r + 0];
            const float4 wc = w[3 * r + 1];
            const float4 wr = w[3 * r + 2];
            acc.x = fmaf(wl.x, left, fmaf(wc.x, m.x, fmaf(wr.x, m.y, acc.x)));
            acc.y = fmaf(wl.y, m.x,  fmaf(wc.y, m.y, fmaf(wr.y, m.z, acc.y)));
            acc.z = fmaf(wl.z, m.y,  fmaf(wc.z, m.z, fmaf(wr.z, m.w, acc.z)));
            acc.w = fmaf(wl.w, m.z,  fmaf(wc.w, m.w, fmaf(wr.w, right, acc.w)));
        }
        if (it < 3) {
            lds4[(cur ^ 1) * LBUF + (ry + 1) * LCELLS + q] = acc;
            __syncthreads();
            cur ^= 1;
        }
    }

    // ---- write final 56x56 tile from registers ----
    if (ry >= 4 && ry < 4 + OTY && q >= 1 && q < 15) {
        const int yo = oy + ry;            // >= 0 here
        const int xo = ox + 4 * q;         // >= 0 here
        if (yo < HH && xo < WW)
            *reinterpret_cast<float4*>(
                out + (size_t)b * HWSZ + (size_t)yo * WW + xo) = acc;
    }
}

extern "C" void kernel_launch(void* const* d_in, const int* in_sizes, int n_in,
                              void* d_out, int out_size, void* d_ws, size_t ws_size,
                              hipStream_t stream) {
    const float* aff  = (const float*)d_in[0];
    const float* feat = (const float*)d_in[1];
    float* out = (float*)d_out;
    (void)d_ws; (void)ws_size;

    dim3 grid(NTX, NTY, BATCH);   // 18 x 10 x 8 = 1440 blocks
    affprop_fused<<<grid, 1024, 0, stream>>>(aff, feat, out);
}

// Round 5
// 40.798 us; speedup vs baseline: 3.6113x; 1.3906x over previous
//
#include <hip/hip_runtime.h>

#define BATCH 8
#define HH 544
#define WW 960
#define HWSZ (HH * WW)
#define OT 56             // output tile edge (56x56), region 64x64
#define LROWS 66          // region rows -1..64 at LDS rows 0..65 (0,65 = zero ring)
#define LCELLS 16         // 16 quads per row; x-halo via shfl
#define LBUF (LROWS * LCELLS)
#define NTX 18            // tiles per image row
#define NTY 10            // tile rows per image
#define TPB (NTX * NTY)   // 180 tiles per batch image

static __device__ __forceinline__ void bar() {
    // raw barrier: order LDS only; leave global prefetch loads in flight
    asm volatile("s_waitcnt lgkmcnt(0)" ::: "memory");
    __builtin_amdgcn_s_barrier();
}

// Persistent: 256 blocks, block p handles batch b=p&7, tiles t_local =
// (p>>3) + 32*j (j=0..NT-1). 2-deep register prefetch pipeline across tiles.
__global__ __launch_bounds__(1024, 4) void affprop_persist(
    const float* __restrict__ aff,
    const float* __restrict__ feat,
    float* __restrict__ out)
{
    __shared__ float4 lds4[2 * LBUF];

    const int tid   = threadIdx.x;
    const int q     = tid & 15;
    const int ry    = tid >> 4;            // 0..63
    const int p     = blockIdx.x;
    const int b     = p & 7;
    const int idx32 = p >> 3;              // 0..31
    const int NT    = (idx32 < TPB - 32 * 5) ? 6 : 5;

    const float* abase = aff  + (size_t)b * 9 * HWSZ;
    const float* fbase = feat + (size_t)b * HWSZ;
    float*       obase = out  + (size_t)b * HWSZ;

    // zero the 4 ring rows (rows 0,65 of both buffers) once; never touched again
    if (tid < 64) {
        const int buf = tid >> 5;
        const int row = ((tid >> 4) & 1) ? (LROWS - 1) : 0;
        lds4[buf * LBUF + row * LCELLS + (tid & 15)] = make_float4(0.f, 0.f, 0.f, 0.f);
    }

    // raw[0..8] = 9 affinity planes, raw[9] = feature quad
    auto issue = [&](int jt, float4 (&raw)[10]) {
        const int tl = idx32 + 32 * jt;
        const int ty = tl / NTX, tx = tl - ty * NTX;
        const int yimg = ty * OT - 4 + ry;
        const int xq   = tx * OT - 4 + 4 * q;
        const bool inp = (yimg >= 0) && (yimg < HH) && (xq >= 0) && (xq < WW);
        const bool wr  = inp && (ry >= 1) && (ry <= 62);
#pragma unroll
        for (int c = 0; c < 10; ++c) raw[c] = make_float4(0.f, 0.f, 0.f, 0.f);
        if (inp)
            raw[9] = *reinterpret_cast<const float4*>(fbase + (size_t)yimg * WW + xq);
        if (wr) {
            const float* ap = abase + (size_t)yimg * WW + xq;
#pragma unroll
            for (int c = 0; c < 9; ++c)
                raw[c] = *reinterpret_cast<const float4*>(ap + (size_t)c * HWSZ);
        }
        __builtin_amdgcn_sched_barrier(0);   // keep load issue here, don't sink
    };

    auto compute = [&](int jt, float4 (&raw)[10]) {
        const int tl = idx32 + 32 * jt;
        const int ty = tl / NTX, tx = tl - ty * NTX;
        const int oy = ty * OT - 4, ox = tx * OT - 4;
        const int yimg = oy + ry;
        const int xq   = ox + 4 * q;
        const bool wr = (yimg >= 0) && (yimg < HH) && (xq >= 0) && (xq < WW)
                        && (ry >= 1) && (ry <= 62);

        // normalize in place (first consume of raw -> counted vmcnt wait here)
        if (wr) {
            float4 s = make_float4(0.f, 0.f, 0.f, 0.f);
#pragma unroll
            for (int c = 0; c < 9; ++c) {
                raw[c].x = fabsf(raw[c].x); s.x += raw[c].x;
                raw[c].y = fabsf(raw[c].y); s.y += raw[c].y;
                raw[c].z = fabsf(raw[c].z); s.z += raw[c].z;
                raw[c].w = fabsf(raw[c].w); s.w += raw[c].w;
            }
            float4 r;
            r.x = 1.0f / s.x; r.y = 1.0f / s.y; r.z = 1.0f / s.z; r.w = 1.0f / s.w;
#pragma unroll
            for (int c = 0; c < 9; ++c) {
                raw[c].x *= r.x; raw[c].y *= r.y; raw[c].z *= r.z; raw[c].w *= r.w;
            }
        }
        // non-wr lanes: raw == 0 -> weights 0 -> acc 0 (preserves zero-pad ring)

        lds4[(ry + 1) * LCELLS + q] = raw[9];   // buf0 f0 store (buf0 quiescent)
        bar();

        float4 acc;
        int bufr = 0;
#pragma unroll
        for (int it = 0; it < 4; ++it) {
            acc = make_float4(0.f, 0.f, 0.f, 0.f);
#pragma unroll
            for (int r = 0; r < 3; ++r) {
                const float4 m = lds4[bufr * LBUF + (ry + r) * LCELLS + q];
                float left  = __shfl_up(m.w, 1);   if (q == 0)  left  = 0.f;
                float right = __shfl_down(m.x, 1); if (q == 15) right = 0.f;
                const float4 wl = raw[3 * r + 0];
                const float4 wc = raw[3 * r + 1];
                const float4 wrr = raw[3 * r + 2];
                acc.x = fmaf(wl.x, left, fmaf(wc.x, m.x, fmaf(wrr.x, m.y, acc.x)));
                acc.y = fmaf(wl.y, m.x,  fmaf(wc.y, m.y, fmaf(wrr.y, m.z, acc.y)));
                acc.z = fmaf(wl.z, m.y,  fmaf(wc.z, m.z, fmaf(wrr.z, m.w, acc.z)));
                acc.w = fmaf(wl.w, m.z,  fmaf(wc.w, m.w, fmaf(wrr.w, right, acc.w)));
            }
            if (it < 3) {
                lds4[(bufr ^ 1) * LBUF + (ry + 1) * LCELLS + q] = acc;
                bar();
                bufr ^= 1;
            }
        }

        if (ry >= 4 && ry < 4 + OT && q >= 1 && q < 15) {
            const int yo = oy + ry, xo = ox + 4 * q;
            if (yo < HH && xo < WW)
                *reinterpret_cast<float4*>(obase + (size_t)yo * WW + xo) = acc;
        }
    };

    float4 A[10], B[10];
    issue(0, A);
    int j = 0;
    while (true) {
        if (j + 1 < NT) issue(j + 1, B);
        compute(j, A);
        if (++j >= NT) break;
        if (j + 1 < NT) issue(j + 1, A);
        compute(j, B);
        if (++j >= NT) break;
    }
}

extern "C" void kernel_launch(void* const* d_in, const int* in_sizes, int n_in,
                              void* d_out, int out_size, void* d_ws, size_t ws_size,
                              hipStream_t stream) {
    const float* aff  = (const float*)d_in[0];
    const float* feat = (const float*)d_in[1];
    float* out = (float*)d_out;
    (void)d_ws; (void)ws_size;

    affprop_persist<<<256, 1024, 0, stream>>>(aff, feat, out);
}